// Round 1
// baseline (5022.618 us; speedup 1.0000x reference)
//
#include <hip/hip_runtime.h>
#include <hip/hip_bf16.h>
#include <float.h>
#include <math.h>

#define B 32
#define NN 999
#define S 1000
#define D 128
#define F 512
#define L 6
#define EPSN 1e-5f

__device__ __forceinline__ float n2n(float v) {
    if (v != v) return 0.f;                       // NaN -> 0
    if (isinf(v)) return v > 0.f ? FLT_MAX : -FLT_MAX;
    return v;
}

// ---------------- embedding ----------------
__global__ __launch_bounds__(128) void k_embed(
        const float* __restrict__ depot, const float* __restrict__ node,
        const float* __restrict__ Wd, const float* __restrict__ bd,
        const float* __restrict__ Wn, const float* __restrict__ bn,
        float* __restrict__ x) {
    int row = blockIdx.x;            // b*S + s
    int b = row / S, s = row % S;
    int d = threadIdx.x;
    float o;
    if (s == 0) {
        float x0 = depot[b * 2 + 0], x1 = depot[b * 2 + 1];
        o = Wd[d * 2 + 0] * x0 + Wd[d * 2 + 1] * x1 + bd[d];
    } else {
        const float* p = node + ((size_t)b * NN + (s - 1)) * 3;
        o = Wn[d * 3 + 0] * p[0] + Wn[d * 3 + 1] * p[1] + Wn[d * 3 + 2] * p[2] + bn[d];
    }
    x[(size_t)row * D + d] = o;
}

// row transform: mode 0 -> row 1 (Win), mode 1 -> row (1-flag)*NN (Wout)
__global__ __launch_bounds__(128) void k_rowxform(
        float* __restrict__ x, const float* __restrict__ W,
        const float* __restrict__ bias, const int* __restrict__ flag, int mode) {
    int b = blockIdx.x;
    int d = threadIdx.x;
    __shared__ float row[D];
    int r = (mode == 0) ? 1 : (1 - flag[b]) * NN;
    float* xr = x + ((size_t)b * S + r) * D;
    row[d] = xr[d];
    __syncthreads();
    float acc = bias[d];
    for (int e = 0; e < D; e += 4) {
        const float4 w = *(const float4*)(W + (size_t)d * D + e);
        acc += w.x * row[e] + w.y * row[e + 1] + w.z * row[e + 2] + w.w * row[e + 3];
    }
    xr[d] = acc;
}

// ---------------- per-layer kernels ----------------
// QKV projection + elementwise prep: sq = sigmoid(q), m = [ek*v || ek]
__global__ __launch_bounds__(128) void k_qkv(
        const float* __restrict__ x,
        const float* __restrict__ Wq, const float* __restrict__ Wk, const float* __restrict__ Wv,
        float* __restrict__ sq, float* __restrict__ m) {
    int r0 = blockIdx.x * 8;         // global row (b*S+s), 8 rows per block
    int d = threadIdx.x;
    __shared__ float xs[8][D];
    for (int r = 0; r < 8; r++) xs[r][d] = x[((size_t)r0 + r) * D + d];
    __syncthreads();
    float aq[8], ak[8], av[8];
#pragma unroll
    for (int r = 0; r < 8; r++) { aq[r] = 0.f; ak[r] = 0.f; av[r] = 0.f; }
    for (int e = 0; e < D; e += 4) {
        float4 wq = *(const float4*)(Wq + (size_t)d * D + e);
        float4 wk = *(const float4*)(Wk + (size_t)d * D + e);
        float4 wv = *(const float4*)(Wv + (size_t)d * D + e);
#pragma unroll
        for (int r = 0; r < 8; r++) {
            float x0 = xs[r][e], x1 = xs[r][e + 1], x2 = xs[r][e + 2], x3 = xs[r][e + 3];
            aq[r] += wq.x * x0 + wq.y * x1 + wq.z * x2 + wq.w * x3;
            ak[r] += wk.x * x0 + wk.y * x1 + wk.z * x2 + wk.w * x3;
            av[r] += wv.x * x0 + wv.y * x1 + wv.z * x2 + wv.w * x3;
        }
    }
    for (int r = 0; r < 8; r++) {
        size_t row = (size_t)r0 + r;
        float ek = __expf(ak[r]);
        sq[row * D + d] = 1.f / (1.f + __expf(-aq[r]));
        m[row * 2 * D + d] = ek * av[r];
        m[row * 2 * D + D + d] = ek;
    }
}

// attention: y = x + sigmoid(q) * (es@(ek*v)) / (es@ek), es = exp(-sc*dist)
__global__ __launch_bounds__(256) void k_attn(
        const float* __restrict__ x, const float* __restrict__ sq,
        const float* __restrict__ m, const float* __restrict__ dist,
        const float* __restrict__ log_scale, const float* __restrict__ alpha, int l,
        float* __restrict__ y) {
    int blk = blockIdx.x;            // B * S/8 blocks
    int b = blk / (S / 8);
    int i0 = (blk % (S / 8)) * 8;
    int tid = threadIdx.x;           // 256
    __shared__ float es[8][S];       // 32 KB
    __shared__ float den[8][D];
    float sc = log_scale[0] * alpha[l];
    const float* dr = dist + ((size_t)b * S + i0) * S;
    for (int t = tid; t < 8 * S; t += 256) {
        int r = t / S, j = t - r * S;
        es[r][j] = __expf(-sc * dr[(size_t)r * S + j]);
    }
    __syncthreads();
    float acc[8];
#pragma unroll
    for (int r = 0; r < 8; r++) acc[r] = 0.f;
    const float* mb = m + (size_t)b * S * 2 * D + tid;
    for (int j = 0; j < S; j++) {
        float mv = mb[(size_t)j * 2 * D];
#pragma unroll
        for (int r = 0; r < 8; r++) acc[r] += es[r][j] * mv;
    }
    if (tid >= D) {
#pragma unroll
        for (int r = 0; r < 8; r++) den[r][tid - D] = acc[r];
    }
    __syncthreads();
    if (tid < D) {
#pragma unroll
        for (int r = 0; r < 8; r++) {
            size_t row = (size_t)b * S + i0 + r;
            float w = n2n(acc[r]) / n2n(den[r][tid]);
            y[row * D + tid] = x[row * D + tid] + sq[row * D + tid] * w;
        }
    }
}

// instance-norm stats: per (b, chunk) partial sums over 125 rows
__global__ __launch_bounds__(128) void k_nstat(
        const float* __restrict__ y, float* __restrict__ part) {
    int b = blockIdx.x >> 3;
    int c = blockIdx.x & 7;
    int d = threadIdx.x;
    const float* p = y + ((size_t)b * S + c * 125) * D + d;
    float s = 0.f, s2 = 0.f;
    for (int r = 0; r < 125; r++) {
        float v = p[(size_t)r * D];
        s += v;
        s2 = fmaf(v, v, s2);
    }
    part[(size_t)blockIdx.x * 2 * D + d] = s;
    part[(size_t)blockIdx.x * 2 * D + D + d] = s2;
}

__global__ __launch_bounds__(256) void k_finalize(
        const float* __restrict__ part, float* __restrict__ acc) {
    int i = blockIdx.x * 256 + threadIdx.x;     // B*2D = 8192
    int b = i / (2 * D), k = i - b * 2 * D;
    float s = 0.f;
    for (int c = 0; c < 8; c++) s += part[(size_t)(b * 8 + c) * 2 * D + k];
    acc[i] = s;
}

__global__ __launch_bounds__(256) void k_norm(
        const float* __restrict__ y, const float* __restrict__ acc,
        const float* __restrict__ g, const float* __restrict__ bb,
        float* __restrict__ out) {
    size_t i = (size_t)blockIdx.x * 256 + threadIdx.x;   // B*S*D
    int d = (int)(i % D);
    int b = (int)(i / ((size_t)S * D));
    float mu = acc[b * 2 * D + d] * (1.f / S);
    float var = acc[b * 2 * D + D + d] * (1.f / S) - mu * mu;
    float v = (y[i] - mu) * rsqrtf(var + EPSN);
    out[i] = v * g[d] + bb[d];
}

__global__ __launch_bounds__(512) void k_ff1(
        const float* __restrict__ h, const float* __restrict__ W1,
        const float* __restrict__ bW1, float* __restrict__ t) {
    int r0 = blockIdx.x * 8;
    int f = threadIdx.x;             // 512
    __shared__ float hs[8][D];
    for (int tt = f; tt < 8 * D; tt += 512) hs[tt / D][tt % D] = h[(size_t)r0 * D + tt];
    __syncthreads();
    float acc[8];
#pragma unroll
    for (int r = 0; r < 8; r++) acc[r] = bW1[f];
    for (int e = 0; e < D; e += 4) {
        float4 w = *(const float4*)(W1 + (size_t)f * D + e);
#pragma unroll
        for (int r = 0; r < 8; r++)
            acc[r] += w.x * hs[r][e] + w.y * hs[r][e + 1] + w.z * hs[r][e + 2] + w.w * hs[r][e + 3];
    }
    for (int r = 0; r < 8; r++)
        t[((size_t)r0 + r) * F + f] = fmaxf(acc[r], 0.f);
}

__global__ __launch_bounds__(128) void k_ff2(
        const float* __restrict__ t, const float* __restrict__ h,
        const float* __restrict__ W2, const float* __restrict__ bW2,
        float* __restrict__ z) {
    int r0 = blockIdx.x * 8;
    int d = threadIdx.x;             // 128
    __shared__ float ts[8][F];       // 16 KB
    for (int tt = d; tt < 8 * F; tt += 128) ts[tt / F][tt % F] = t[(size_t)r0 * F + tt];
    __syncthreads();
    float acc[8];
#pragma unroll
    for (int r = 0; r < 8; r++) acc[r] = bW2[d];
    for (int e = 0; e < F; e += 4) {
        float4 w = *(const float4*)(W2 + (size_t)d * F + e);
#pragma unroll
        for (int r = 0; r < 8; r++)
            acc[r] += w.x * ts[r][e] + w.y * ts[r][e + 1] + w.z * ts[r][e + 2] + w.w * ts[r][e + 3];
    }
    for (int r = 0; r < 8; r++) {
        size_t row = (size_t)r0 + r;
        z[row * D + d] = h[row * D + d] + acc[r];
    }
}

extern "C" void kernel_launch(void* const* d_in, const int* in_sizes, int n_in,
                              void* d_out, int out_size, void* d_ws, size_t ws_size,
                              hipStream_t stream) {
    const float* depot = (const float*)d_in[0];
    const float* node  = (const float*)d_in[1];
    const float* dist  = (const float*)d_in[2];
    const float* log_scale = (const float*)d_in[3];
    const int*   flag  = (const int*)d_in[4];
    const float* Wd   = (const float*)d_in[5];
    const float* bd   = (const float*)d_in[6];
    const float* Wn   = (const float*)d_in[7];
    const float* bn   = (const float*)d_in[8];
    const float* Win  = (const float*)d_in[9];
    const float* bin_ = (const float*)d_in[10];
    const float* Wout = (const float*)d_in[11];
    const float* bout = (const float*)d_in[12];
    const float* Wq   = (const float*)d_in[13];
    const float* Wk   = (const float*)d_in[14];
    const float* Wv   = (const float*)d_in[15];
    const float* alpha= (const float*)d_in[16];
    const float* g1   = (const float*)d_in[17];
    const float* b1   = (const float*)d_in[18];
    const float* W1   = (const float*)d_in[19];
    const float* bW1  = (const float*)d_in[20];
    const float* W2   = (const float*)d_in[21];
    const float* bW2  = (const float*)d_in[22];
    const float* g2   = (const float*)d_in[23];
    const float* b2   = (const float*)d_in[24];

    float* ws = (float*)d_ws;
    size_t nxd = (size_t)B * S * D;
    float* x    = ws;                       // B*S*D
    float* sq   = x + nxd;                  // B*S*D
    float* m    = sq + nxd;                 // B*S*2D
    float* y    = m + 2 * nxd;              // B*S*D
    float* h    = y + nxd;                  // B*S*D
    float* t    = h + nxd;                  // B*S*F
    float* part = t + (size_t)B * S * F;    // B*8*2*D
    float* acc  = part + (size_t)B * 8 * 2 * D;  // B*2*D

    k_embed<<<B * S, 128, 0, stream>>>(depot, node, Wd, bd, Wn, bn, x);
    k_rowxform<<<B, 128, 0, stream>>>(x, Win, bin_, flag, 0);
    k_rowxform<<<B, 128, 0, stream>>>(x, Wout, bout, flag, 1);

    for (int l = 0; l < L; l++) {
        k_qkv<<<B * S / 8, 128, 0, stream>>>(x, Wq + (size_t)l * D * D,
                                             Wk + (size_t)l * D * D,
                                             Wv + (size_t)l * D * D, sq, m);
        k_attn<<<B * S / 8, 256, 0, stream>>>(x, sq, m, dist, log_scale, alpha, l, y);
        k_nstat<<<B * 8, 128, 0, stream>>>(y, part);
        k_finalize<<<32, 256, 0, stream>>>(part, acc);
        k_norm<<<B * S * D / 256, 256, 0, stream>>>(y, acc, g1 + l * D, b1 + l * D, h);
        k_ff1<<<B * S / 8, 512, 0, stream>>>(h, W1 + (size_t)l * F * D, bW1 + (size_t)l * F, t);
        k_ff2<<<B * S / 8, 128, 0, stream>>>(t, h, W2 + (size_t)l * D * F, bW2 + (size_t)l * D, y);
        k_nstat<<<B * 8, 128, 0, stream>>>(y, part);
        k_finalize<<<32, 256, 0, stream>>>(part, acc);
        float* dst = (l == L - 1) ? (float*)d_out : x;
        k_norm<<<B * S * D / 256, 256, 0, stream>>>(y, acc, g2 + l * D, b2 + l * D, dst);
    }
}

// Round 2
// 1163.039 us; speedup vs baseline: 4.3185x; 4.3185x over previous
//
#include <hip/hip_runtime.h>
#include <hip/hip_bf16.h>
#include <float.h>
#include <math.h>

#define B 32
#define NN 999
#define S 1000
#define SP 1024
#define D 128
#define F 512
#define L 6
#define EPSN 1e-5f

typedef __attribute__((ext_vector_type(4))) float f32x4;
typedef __attribute__((ext_vector_type(4))) short s16x4;

#if defined(__has_builtin)
#if __has_builtin(__builtin_amdgcn_mfma_f32_16x16x16bf16_1k)
#define HAVE_MFMA_BUILTIN 1
#endif
#endif

#ifdef HAVE_MFMA_BUILTIN
#define MFMA(a, b, c) __builtin_amdgcn_mfma_f32_16x16x16bf16_1k((a), (b), (c), 0, 0, 0)
#else
static __device__ __forceinline__ f32x4 mfma_asm(s16x4 a, s16x4 b, f32x4 c) {
    asm volatile("v_mfma_f32_16x16x16_bf16 %0, %1, %2, %0\n\ts_nop 7\n\ts_nop 7"
                 : "+v"(c) : "v"(a), "v"(b));
    return c;
}
#define MFMA(a, b, c) mfma_asm((a), (b), (c))
#endif

__device__ __forceinline__ float n2n(float v) {
    if (v != v) return 0.f;
    if (isinf(v)) return v > 0.f ? FLT_MAX : -FLT_MAX;
    return v;
}

__device__ __forceinline__ unsigned short f2bf(float x) {
    unsigned u = __float_as_uint(x);
    return (unsigned short)((u + 0x7fffu + ((u >> 16) & 1u)) >> 16);
}

// load 8 f32 from global, convert to bf16, store to LDS (two b64 writes)
__device__ __forceinline__ void cvt_store8(unsigned short* lp, const float* gp) {
    float4 a = *(const float4*)gp;
    float4 b = *(const float4*)(gp + 4);
    s16x4 p0 = {(short)f2bf(a.x), (short)f2bf(a.y), (short)f2bf(a.z), (short)f2bf(a.w)};
    s16x4 p1 = {(short)f2bf(b.x), (short)f2bf(b.y), (short)f2bf(b.z), (short)f2bf(b.w)};
    *(s16x4*)lp = p0;
    *(s16x4*)(lp + 4) = p1;
}

// ---------------- embedding ----------------
__global__ __launch_bounds__(128) void k_embed(
        const float* __restrict__ depot, const float* __restrict__ node,
        const float* __restrict__ Wd, const float* __restrict__ bd,
        const float* __restrict__ Wn, const float* __restrict__ bn,
        float* __restrict__ x) {
    int row = blockIdx.x;
    int b = row / S, s = row % S;
    int d = threadIdx.x;
    float o;
    if (s == 0) {
        float x0 = depot[b * 2 + 0], x1 = depot[b * 2 + 1];
        o = Wd[d * 2 + 0] * x0 + Wd[d * 2 + 1] * x1 + bd[d];
    } else {
        const float* p = node + ((size_t)b * NN + (s - 1)) * 3;
        o = Wn[d * 3 + 0] * p[0] + Wn[d * 3 + 1] * p[1] + Wn[d * 3 + 2] * p[2] + bn[d];
    }
    x[(size_t)row * D + d] = o;
}

__global__ __launch_bounds__(128) void k_rowxform(
        float* __restrict__ x, const float* __restrict__ W,
        const float* __restrict__ bias, const int* __restrict__ flag, int mode) {
    int b = blockIdx.x;
    int d = threadIdx.x;
    __shared__ float row[D];
    int r = (mode == 0) ? 1 : (1 - flag[b]) * NN;
    float* xr = x + ((size_t)b * S + r) * D;
    row[d] = xr[d];
    __syncthreads();
    float acc = bias[d];
    for (int e = 0; e < D; e += 4) {
        const float4 w = *(const float4*)(W + (size_t)d * D + e);
        acc += w.x * row[e] + w.y * row[e + 1] + w.z * row[e + 2] + w.w * row[e + 3];
    }
    xr[d] = acc;
}

// ---------------- qkv GEMM (MFMA): sq = sigmoid(q), m = [ek*v || ek] bf16 ----------------
__global__ __launch_bounds__(256) void k_qkv(
        const float* __restrict__ x,
        const float* __restrict__ Wq, const float* __restrict__ Wk, const float* __restrict__ Wv,
        float* __restrict__ sq, unsigned short* __restrict__ m) {
    int blk = blockIdx.x;
    int b = blk >> 4, rb = blk & 15;
    int s0 = rb * 64;
    int tid = threadIdx.x, lane = tid & 63, wid = tid >> 6;
    __shared__ unsigned short xs[64 * 40];
    __shared__ unsigned short wt[3][128 * 40];
    f32x4 acc[3][8];
#pragma unroll
    for (int mm = 0; mm < 3; mm++)
#pragma unroll
        for (int cf = 0; cf < 8; cf++) acc[mm][cf] = {0.f, 0.f, 0.f, 0.f};

    for (int k0 = 0; k0 < D; k0 += 32) {
        {
            int i = tid >> 2, kq = (tid & 3) * 8;
            int s = s0 + i;
            int gs = s < S ? s : S - 1;
            cvt_store8(&xs[i * 40 + kq], x + ((size_t)b * S + gs) * D + k0 + kq);
        }
#pragma unroll
        for (int u0 = 0; u0 < 6; u0++) {
            int u = tid + u0 * 256;
            int mm = u >> 9;
            int v = u & 511;
            int c = v >> 2, kq = (v & 3) * 8;
            const float* Wsrc = (mm == 0) ? Wq : (mm == 1) ? Wk : Wv;
            cvt_store8(&wt[mm][c * 40 + kq], Wsrc + (size_t)c * D + k0 + kq);
        }
        __syncthreads();
#pragma unroll
        for (int ks = 0; ks < 2; ks++) {
            int ko = ks * 16 + (lane >> 4) * 4;
            s16x4 a = *(const s16x4*)&xs[(wid * 16 + (lane & 15)) * 40 + ko];
#pragma unroll
            for (int mm = 0; mm < 3; mm++)
#pragma unroll
                for (int cf = 0; cf < 8; cf++) {
                    s16x4 bf = *(const s16x4*)&wt[mm][(cf * 16 + (lane & 15)) * 40 + ko];
                    acc[mm][cf] = MFMA(a, bf, acc[mm][cf]);
                }
        }
        __syncthreads();
    }
#pragma unroll
    for (int cf = 0; cf < 8; cf++) {
        int d = cf * 16 + (lane & 15);
#pragma unroll
        for (int r = 0; r < 4; r++) {
            int s = s0 + wid * 16 + (lane >> 4) * 4 + r;
            size_t mo = ((size_t)b * SP + s) * 256;
            if (s < S) {
                float qv = acc[0][cf][r], kv = acc[1][cf][r], vv = acc[2][cf][r];
                float ek = __expf(kv);
                size_t xo = ((size_t)b * S + s) * D + d;
                sq[xo] = 1.f / (1.f + __expf(-qv));
                m[mo + d] = f2bf(ek * vv);
                m[mo + 128 + d] = f2bf(ek);
            } else {
                m[mo + d] = 0;
                m[mo + 128 + d] = 0;
            }
        }
    }
}

// ---------------- attention (MFMA): y = x + sq * (es@ekv)/(es@ek) ----------------
__global__ __launch_bounds__(512) void k_attn(
        const float* __restrict__ x, const float* __restrict__ sq,
        const unsigned short* __restrict__ m, const float* __restrict__ dist,
        const float* __restrict__ log_scale, const float* __restrict__ alpha, int l,
        float* __restrict__ y) {
    int blk = blockIdx.x;
    int b = blk >> 3, ib = blk & 7;
    int i0 = ib * 128;
    int tid = threadIdx.x, lane = tid & 63, wid = tid >> 6;
    int wr = wid >> 1, wc = wid & 1;
    __shared__ unsigned short esL[128 * 40];
    __shared__ unsigned short mtL[256 * 40];
    float sc = log_scale[0] * alpha[l];
    const unsigned short* mb = m + (size_t)b * SP * 256;
    const float* db = dist + (size_t)b * S * S;
    f32x4 acc[2][8];
#pragma unroll
    for (int rf = 0; rf < 2; rf++)
#pragma unroll
        for (int cf = 0; cf < 8; cf++) acc[rf][cf] = {0.f, 0.f, 0.f, 0.f};

    for (int k0 = 0; k0 < SP; k0 += 32) {
        // stage es[128][32] bf16 (computed from dist)
        {
            int i = tid >> 2, kq = (tid & 3) * 8;
            int gi = i0 + i;
            if (gi >= S) gi = S - 1;
            const float* dp = db + (size_t)gi * S + k0 + kq;
            float v[8];
            if (k0 + 32 <= S) {
                float4 a0 = *(const float4*)dp, a1 = *(const float4*)(dp + 4);
                v[0] = a0.x; v[1] = a0.y; v[2] = a0.z; v[3] = a0.w;
                v[4] = a1.x; v[5] = a1.y; v[6] = a1.z; v[7] = a1.w;
#pragma unroll
                for (int j = 0; j < 8; j++) v[j] = __expf(-sc * v[j]);
            } else {
#pragma unroll
                for (int j = 0; j < 8; j++) {
                    int kk = k0 + kq + j;
                    v[j] = (kk < S) ? __expf(-sc * dp[j]) : 0.f;
                }
            }
            s16x4 p0 = {(short)f2bf(v[0]), (short)f2bf(v[1]), (short)f2bf(v[2]), (short)f2bf(v[3])};
            s16x4 p1 = {(short)f2bf(v[4]), (short)f2bf(v[5]), (short)f2bf(v[6]), (short)f2bf(v[7])};
            *(s16x4*)&esL[i * 40 + kq] = p0;
            *(s16x4*)&esL[i * 40 + kq + 4] = p1;
        }
        // stage mT[256][32]: in-register 4x4 transpose
        {
            int ku = wid;
            int cu = lane * 4;
            const unsigned short* mp = mb + ((size_t)(k0 + ku * 4) * 256 + cu);
            s16x4 q0 = *(const s16x4*)mp;
            s16x4 q1 = *(const s16x4*)(mp + 256);
            s16x4 q2 = *(const s16x4*)(mp + 512);
            s16x4 q3 = *(const s16x4*)(mp + 768);
#pragma unroll
            for (int j = 0; j < 4; j++) {
                int cc = (j + lane) & 3;
                s16x4 w = {q0[cc], q1[cc], q2[cc], q3[cc]};
                *(s16x4*)&mtL[(cu + cc) * 40 + ku * 4] = w;
            }
        }
        __syncthreads();
#pragma unroll
        for (int ks = 0; ks < 2; ks++) {
            int ko = ks * 16 + (lane >> 4) * 4;
            s16x4 a0 = *(const s16x4*)&esL[(wr * 32 + (lane & 15)) * 40 + ko];
            s16x4 a1 = *(const s16x4*)&esL[(wr * 32 + 16 + (lane & 15)) * 40 + ko];
#pragma unroll
            for (int cf = 0; cf < 8; cf++) {
                int cg = wc * 64 + (cf & 3) * 16 + (cf >> 2) * 128;
                s16x4 bf = *(const s16x4*)&mtL[(cg + (lane & 15)) * 40 + ko];
                acc[0][cf] = MFMA(a0, bf, acc[0][cf]);
                acc[1][cf] = MFMA(a1, bf, acc[1][cf]);
            }
        }
        __syncthreads();
    }
#pragma unroll
    for (int cf = 0; cf < 4; cf++) {
        int d = wc * 64 + cf * 16 + (lane & 15);
#pragma unroll
        for (int rf = 0; rf < 2; rf++)
#pragma unroll
            for (int r = 0; r < 4; r++) {
                int i = i0 + wr * 32 + rf * 16 + (lane >> 4) * 4 + r;
                if (i < S) {
                    size_t off = ((size_t)b * S + i) * D + d;
                    float w = n2n(acc[rf][cf][r]) / n2n(acc[rf][cf + 4][r]);
                    y[off] = x[off] + sq[off] * w;
                }
            }
    }
}

// ---------------- instance-norm ----------------
__global__ __launch_bounds__(128) void k_nstat(
        const float* __restrict__ y, float* __restrict__ part) {
    int b = blockIdx.x >> 3;
    int c = blockIdx.x & 7;
    int d = threadIdx.x;
    const float* p = y + ((size_t)b * S + c * 125) * D + d;
    float s = 0.f, s2 = 0.f;
    for (int r = 0; r < 125; r++) {
        float v = p[(size_t)r * D];
        s += v;
        s2 = fmaf(v, v, s2);
    }
    part[(size_t)blockIdx.x * 2 * D + d] = s;
    part[(size_t)blockIdx.x * 2 * D + D + d] = s2;
}

__global__ __launch_bounds__(256) void k_finalize(
        const float* __restrict__ part, float* __restrict__ acc) {
    int i = blockIdx.x * 256 + threadIdx.x;
    int b = i / (2 * D), k = i - b * 2 * D;
    float s = 0.f;
    for (int c = 0; c < 8; c++) s += part[(size_t)(b * 8 + c) * 2 * D + k];
    acc[i] = s;
}

__global__ __launch_bounds__(256) void k_norm(
        const float* __restrict__ y, const float* __restrict__ acc,
        const float* __restrict__ g, const float* __restrict__ bb,
        float* __restrict__ out) {
    size_t i = (size_t)blockIdx.x * 256 + threadIdx.x;
    int d = (int)(i % D);
    int b = (int)(i / ((size_t)S * D));
    float mu = acc[b * 2 * D + d] * (1.f / S);
    float var = acc[b * 2 * D + D + d] * (1.f / S) - mu * mu;
    float v = (y[i] - mu) * rsqrtf(var + EPSN);
    out[i] = v * g[d] + bb[d];
}

// ---------------- FFN (MFMA) ----------------
__global__ __launch_bounds__(256) void k_ff1(
        const float* __restrict__ h, const float* __restrict__ W1,
        const float* __restrict__ bW1, unsigned short* __restrict__ t) {
    int blk = blockIdx.x;
    int rb = blk >> 1, cb = blk & 1;
    int r0 = rb * 64, c0 = cb * 256;
    int tid = threadIdx.x, lane = tid & 63, wid = tid >> 6;
    __shared__ unsigned short hs[64 * 40];
    __shared__ unsigned short ws[256 * 40];
    f32x4 acc[16];
#pragma unroll
    for (int cf = 0; cf < 16; cf++) acc[cf] = {0.f, 0.f, 0.f, 0.f};

    for (int k0 = 0; k0 < D; k0 += 32) {
        {
            int i = tid >> 2, kq = (tid & 3) * 8;
            cvt_store8(&hs[i * 40 + kq], h + (size_t)(r0 + i) * D + k0 + kq);
        }
#pragma unroll
        for (int kq8 = 0; kq8 < 4; kq8++)
            cvt_store8(&ws[tid * 40 + kq8 * 8], W1 + (size_t)(c0 + tid) * D + k0 + kq8 * 8);
        __syncthreads();
#pragma unroll
        for (int ks = 0; ks < 2; ks++) {
            int ko = ks * 16 + (lane >> 4) * 4;
            s16x4 a = *(const s16x4*)&hs[(wid * 16 + (lane & 15)) * 40 + ko];
#pragma unroll
            for (int cf = 0; cf < 16; cf++) {
                s16x4 bf = *(const s16x4*)&ws[(cf * 16 + (lane & 15)) * 40 + ko];
                acc[cf] = MFMA(a, bf, acc[cf]);
            }
        }
        __syncthreads();
    }
#pragma unroll
    for (int cf = 0; cf < 16; cf++) {
        int c = c0 + cf * 16 + (lane & 15);
        float bias = bW1[c];
#pragma unroll
        for (int r = 0; r < 4; r++) {
            int row = r0 + wid * 16 + (lane >> 4) * 4 + r;
            float v = acc[cf][r] + bias;
            t[(size_t)row * F + c] = f2bf(fmaxf(v, 0.f));
        }
    }
}

__global__ __launch_bounds__(256) void k_ff2(
        const unsigned short* __restrict__ t, const float* __restrict__ h,
        const float* __restrict__ W2, const float* __restrict__ bW2,
        float* __restrict__ y) {
    int blk = blockIdx.x;
    int r0 = blk * 64;
    int tid = threadIdx.x, lane = tid & 63, wid = tid >> 6;
    __shared__ unsigned short ts[64 * 40];
    __shared__ unsigned short ws[128 * 40];
    f32x4 acc[8];
#pragma unroll
    for (int cf = 0; cf < 8; cf++) acc[cf] = {0.f, 0.f, 0.f, 0.f};

    for (int k0 = 0; k0 < F; k0 += 32) {
        {
            int i = tid >> 2, kq = (tid & 3) * 8;
            const unsigned short* tp = t + (size_t)(r0 + i) * F + k0 + kq;
            s16x4 v0 = *(const s16x4*)tp;
            s16x4 v1 = *(const s16x4*)(tp + 4);
            *(s16x4*)&ts[i * 40 + kq] = v0;
            *(s16x4*)&ts[i * 40 + kq + 4] = v1;
        }
        {
            int c = tid >> 1, kq = (tid & 1) * 16;
            cvt_store8(&ws[c * 40 + kq], W2 + (size_t)c * F + k0 + kq);
            cvt_store8(&ws[c * 40 + kq + 8], W2 + (size_t)c * F + k0 + kq + 8);
        }
        __syncthreads();
#pragma unroll
        for (int ks = 0; ks < 2; ks++) {
            int ko = ks * 16 + (lane >> 4) * 4;
            s16x4 a = *(const s16x4*)&ts[(wid * 16 + (lane & 15)) * 40 + ko];
#pragma unroll
            for (int cf = 0; cf < 8; cf++) {
                s16x4 bf = *(const s16x4*)&ws[(cf * 16 + (lane & 15)) * 40 + ko];
                acc[cf] = MFMA(a, bf, acc[cf]);
            }
        }
        __syncthreads();
    }
#pragma unroll
    for (int cf = 0; cf < 8; cf++) {
        int c = cf * 16 + (lane & 15);
        float bias = bW2[c];
#pragma unroll
        for (int r = 0; r < 4; r++) {
            int row = r0 + wid * 16 + (lane >> 4) * 4 + r;
            size_t off = (size_t)row * D + c;
            y[off] = h[off] + acc[cf][r] + bias;
        }
    }
}

extern "C" void kernel_launch(void* const* d_in, const int* in_sizes, int n_in,
                              void* d_out, int out_size, void* d_ws, size_t ws_size,
                              hipStream_t stream) {
    const float* depot = (const float*)d_in[0];
    const float* node  = (const float*)d_in[1];
    const float* dist  = (const float*)d_in[2];
    const float* log_scale = (const float*)d_in[3];
    const int*   flag  = (const int*)d_in[4];
    const float* Wd   = (const float*)d_in[5];
    const float* bd   = (const float*)d_in[6];
    const float* Wn   = (const float*)d_in[7];
    const float* bn   = (const float*)d_in[8];
    const float* Win  = (const float*)d_in[9];
    const float* bin_ = (const float*)d_in[10];
    const float* Wout = (const float*)d_in[11];
    const float* bout = (const float*)d_in[12];
    const float* Wq   = (const float*)d_in[13];
    const float* Wk   = (const float*)d_in[14];
    const float* Wv   = (const float*)d_in[15];
    const float* alpha= (const float*)d_in[16];
    const float* g1   = (const float*)d_in[17];
    const float* b1   = (const float*)d_in[18];
    const float* W1   = (const float*)d_in[19];
    const float* bW1  = (const float*)d_in[20];
    const float* W2   = (const float*)d_in[21];
    const float* bW2  = (const float*)d_in[22];
    const float* g2   = (const float*)d_in[23];
    const float* b2   = (const float*)d_in[24];

    float* ws = (float*)d_ws;
    size_t nxd = (size_t)B * S * D;                       // 4,096,000
    float* x    = ws;
    float* sqb  = ws + nxd;
    float* y    = ws + 2 * nxd;
    float* h    = ws + 3 * nxd;
    float* part = ws + 4 * nxd;                           // 65536
    float* accb = part + (size_t)B * 8 * 2 * D;           // 8192
    unsigned short* m = (unsigned short*)(accb + (size_t)B * 2 * D);
    unsigned short* t = m + (size_t)B * SP * 256;

    k_embed<<<B * S, 128, 0, stream>>>(depot, node, Wd, bd, Wn, bn, x);
    k_rowxform<<<B, 128, 0, stream>>>(x, Win, bin_, flag, 0);
    k_rowxform<<<B, 128, 0, stream>>>(x, Wout, bout, flag, 1);

    for (int l = 0; l < L; l++) {
        k_qkv<<<B * 16, 256, 0, stream>>>(x, Wq + (size_t)l * D * D,
                                          Wk + (size_t)l * D * D,
                                          Wv + (size_t)l * D * D, sqb, m);
        k_attn<<<B * 8, 512, 0, stream>>>(x, sqb, m, dist, log_scale, alpha, l, y);
        k_nstat<<<B * 8, 128, 0, stream>>>(y, part);
        k_finalize<<<32, 256, 0, stream>>>(part, accb);
        k_norm<<<B * S * D / 256, 256, 0, stream>>>(y, accb, g1 + l * D, b1 + l * D, h);
        k_ff1<<<(B * S / 64) * 2, 256, 0, stream>>>(h, W1 + (size_t)l * F * D, bW1 + (size_t)l * F, t);
        k_ff2<<<B * S / 64, 256, 0, stream>>>(t, h, W2 + (size_t)l * D * F, bW2 + (size_t)l * D, y);
        k_nstat<<<B * 8, 128, 0, stream>>>(y, part);
        k_finalize<<<32, 256, 0, stream>>>(part, accb);
        float* dst = (l == L - 1) ? (float*)d_out : x;
        k_norm<<<B * S * D / 256, 256, 0, stream>>>(y, accb, g2 + l * D, b2 + l * D, dst);
    }
}